// Round 20
// baseline (621.033 us; speedup 1.0000x reference)
//
#include <hip/hip_runtime.h>
#include <hip/hip_bf16.h>

// DGCNN-style KNN classifier. B=8, N=2048, K=10.
// g_flag=1 -> bf16 inputs, 0 -> fp32 (runtime probe). Output same dtype.
// Scratch in static __device__ globals; every byte read is written earlier in
// the same launch (graph-replay safe; norms/g_th re-initialized each launch).
//
// R19->R20: (1) sd XOR-swizzle col^=4*((row>>2)&7): kills the 8-way phase-1
// read conflict (row stride 68 == 4 mod 32 put lanes 8 apart in one bank;
// measured 1.45M conflicts). float4 alignment preserved; write side mirrored.
// (2) next tile's kt=0 B-fragments prefetched into regs BEFORE the scan so
// their L2 latency overlaps the VALU-only scan phase.

#define NEG 0.2f
#define FMAX 3.402823466e+38f
#define FMAXB 0x7F7FFFFFu
#define KINIT 0x7F7FFFFFFFFFFFFFull  // (FLT_MAX bits << 32) | 0xFFFFFFFF

typedef __hip_bfloat16 bf16;
typedef __attribute__((ext_vector_type(8))) short s8v;    // 8 bf16
typedef __attribute__((ext_vector_type(4))) float f32x4;  // MFMA acc
typedef unsigned long long u64;

#define BB 8
#define NN 2048
#define BNTOT (BB * NN)
#define NPART 4

#define OFF_NORMS ((size_t)0)
#define OFF_PART (OFF_NORMS + BNTOT)
#define OFF_POOLED (OFF_PART + 8 * 1024 * 32)
#define OFF_H1 (OFF_POOLED + 8 * 1024)
#define OFF_H2 (OFF_H1 + 8 * 512)
#define WSF_TOTAL (OFF_H2 + 8 * 256)

// frag-tiled W1..W4 halves: base[l] + z*half[l] + i
#define WB1 0
#define WB2 4096
#define WB3 12288
#define WB4 28672
#define WTOT 94208

__device__ float g_ws_f[WSF_TOTAL];
__device__ float g_G[(size_t)8 * BNTOT * 64];     // [chunk(<=4)][z(2)][BN][64]
__device__ u64 g_pk[(size_t)BNTOT * NPART * 10];  // partial top-10 packed keys
__device__ unsigned g_th[BNTOT];                  // per-query dist bound (fp32 bits)
__device__ int g_flag;                            // 1 = bf16 inputs, 0 = fp32
__device__ unsigned short g_hi[(size_t)BNTOT * 512];    // knn/gmat split (frag-tiled)
__device__ unsigned short g_lo[(size_t)BNTOT * 512];
__device__ unsigned short g_xhi5[(size_t)BNTOT * 512];  // W5-layout activations
__device__ unsigned short g_xlo5[(size_t)BNTOT * 512];
__device__ unsigned short g_whi[1024 * 512];            // split W5 weights
__device__ unsigned short g_wlo[1024 * 512];
__device__ unsigned short g_wfh[WTOT];                  // split W1..W4 (frag-tiled)
__device__ unsigned short g_wfl[WTOT];

__device__ __forceinline__ float ldany(const void* p, size_t i, int isb) {
  if (isb) return __bfloat162float(((const bf16*)p)[i]);
  return ((const float*)p)[i];
}

// ---------------- dtype probe ----------------
__global__ void probe_kernel(const void* pts) {
  const unsigned* w = (const unsigned*)pts;
  int cnt = 0;
  for (int i = 0; i < 256; ++i) {
    unsigned e2 = (w[i] >> 7) & 0xFF;
    cnt += (e2 >= 110 && e2 <= 135);
  }
  g_flag = (cnt > 128) ? 1 : 0;
}

// ---------------- norms (layer-1 input only) + g_th init ----------------
__global__ void norms_kernel(const void* xraw, int lda, int C, int BN) {
  const int isb = g_flag;
  float* norms = g_ws_f + OFF_NORMS;
  int row = blockIdx.x * (blockDim.x >> 6) + (threadIdx.x >> 6);
  int lane = threadIdx.x & 63;
  if (row >= BN) return;
  float s = 0.f;
  for (int c = lane; c < C; c += 64) {
    float v = ldany(xraw, (size_t)row * lda + c, isb);
    s += v * v;
  }
#pragma unroll
  for (int off = 32; off > 0; off >>= 1) s += __shfl_down(s, off, 64);
  if (lane == 0) { norms[row] = s; g_th[row] = FMAXB; }
}

__global__ void zero_norms() {
  int i = blockIdx.x * blockDim.x + threadIdx.x;
  if (i < BNTOT) g_ws_f[OFF_NORMS + i] = 0.f;
}

// ------- split-bf16 into MFMA-fragment-tile layout (points + W5 weights) -------
__global__ void split_kernel(const void* xraw, int lda, int C,
                             int csh2, int dst, int total) {
  int i = blockIdx.x * blockDim.x + threadIdx.x;
  if (i >= total) return;
  const int isb = g_flag;
  int t = i >> 9, win = i & 511;
  int quad = win >> 7, l16 = (win >> 3) & 15, j = win & 7;
  int ktiles_m1 = (1 << csh2) - 1;
  int rg = t >> csh2, kt = t & ktiles_m1;
  int r = rg * 16 + l16;
  int c = kt * 32 + quad * 8 + j;
  float v = (c < C) ? ldany(xraw, (size_t)r * lda + c, isb) : 0.f;
  bf16 h = __float2bfloat16(v);
  float hf = __bfloat162float(h);
  bf16 l = __float2bfloat16(v - hf);
  unsigned short* H = dst ? g_whi : g_hi;
  unsigned short* L = dst ? g_wlo : g_lo;
  H[i] = *(unsigned short*)&h;
  L[i] = *(unsigned short*)&l;
}

// ------- split W-halves (W1..W4) into frag-tiled g_wfh/g_wfl; z = blockIdx.y -------
__global__ void split_w(const void* W, int C, int ktsh, int wbase, int whalf,
                        int total) {
  int i = blockIdx.x * blockDim.x + threadIdx.x;
  if (i >= total) return;
  int z = blockIdx.y;
  const int isb = g_flag;
  int t = i >> 9, win = i & 511;
  int quad = win >> 7, l16 = (win >> 3) & 15, j = win & 7;
  int rg = t >> ktsh, kt = t & ((1 << ktsh) - 1);
  int orow = rg * 16 + l16;
  int c = kt * 32 + quad * 8 + j;
  float v = (c < C) ? ldany(W, (size_t)orow * (2 * C) + (size_t)z * C + c, isb) : 0.f;
  bf16 h = __float2bfloat16(v);
  float hf = __bfloat162float(h);
  bf16 l = __float2bfloat16(v - hf);
  g_wfh[wbase + z * whalf + i] = *(unsigned short*)&h;
  g_wfl[wbase + z * whalf + i] = *(unsigned short*)&l;
}

// sd swizzle: element (row, col) -> row*68 + (col ^ (4*((row>>2)&7)))
__device__ __forceinline__ int sdx(int row, int col) {
  return row * 68 + (col ^ (4 * ((row >> 2) & 7)));
}

// ------- fused KNN (partitioned): MFMA distances + per-partition top-10 -------
// Double-buffered swizzled sd (one barrier/tile); grid-global threshold g_th;
// next-tile kt=0 B-fragments prefetched before the scan.
template <int CPAD>
__global__ __launch_bounds__(256) void knn_fused(int N) {
  constexpr int KT = CPAD >> 5;
  __shared__ __align__(16) float sdbuf[2][64 * 68];  // 34816 B
  const int tid = threadIdx.x;
  const int wave = tid >> 6, lane = tid & 63;
  const int quad = lane >> 4, l16 = lane & 15;
  const int b = blockIdx.y;
  const int q0 = blockIdx.x * 64;
  const int part = blockIdx.z;
  const int PN = N / NPART;
  const size_t rowb = (size_t)b * N;
  const float* norms = g_ws_f + OFF_NORMS;

  const int arg = (int)((rowb + q0) >> 4) + wave;
  s8v ah[KT], al[KT];
#pragma unroll
  for (int kt = 0; kt < KT; ++kt) {
    const size_t abase = ((size_t)arg * KT + kt) * 512 + lane * 8;
    ah[kt] = *(const s8v*)(g_hi + abase);
    al[kt] = *(const s8v*)(g_lo + abase);
  }

  const int selfn = q0 + lane;  // this thread maintains query q0+lane
  const float qn = norms[rowb + selfn];
  u64 K[10];
#pragma unroll
  for (int i = 0; i < 10; ++i) K[i] = KINIT;
  unsigned gth = FMAXB;  // cached grid-wide bound (fp32 bits)

  // prefetch kt=0 B-fragments of the first tile
  const int m0first = part * PN;
  s8v pbh[4], pbl[4];
  {
    const int brg0 = (int)((rowb + m0first) >> 4);
#pragma unroll
    for (int s = 0; s < 4; ++s) {
      const size_t bbase = ((size_t)(brg0 + s) * KT) * 512 + lane * 8;
      pbh[s] = *(const s8v*)(g_hi + bbase);
      pbl[s] = *(const s8v*)(g_lo + bbase);
    }
  }

  int pb = 0;
  for (int m0 = m0first; m0 < (part + 1) * PN; m0 += 64, pb ^= 1) {
    f32x4 acc[4];
#pragma unroll
    for (int s = 0; s < 4; ++s) acc[s] = (f32x4){0.f, 0.f, 0.f, 0.f};
    const int brg0 = (int)((rowb + m0) >> 4);
    // kt = 0 uses the prefetched fragments
#pragma unroll
    for (int s = 0; s < 4; ++s) {
      acc[s] = __builtin_amdgcn_mfma_f32_16x16x32_bf16(ah[0], pbh[s], acc[s], 0, 0, 0);
      acc[s] = __builtin_amdgcn_mfma_f32_16x16x32_bf16(ah[0], pbl[s], acc[s], 0, 0, 0);
      acc[s] = __builtin_amdgcn_mfma_f32_16x16x32_bf16(al[0], pbh[s], acc[s], 0, 0, 0);
    }
#pragma unroll
    for (int kt = 1; kt < KT; ++kt) {
#pragma unroll
      for (int s = 0; s < 4; ++s) {
        const size_t bbase = ((size_t)(brg0 + s) * KT + kt) * 512 + lane * 8;
        s8v bh = *(const s8v*)(g_hi + bbase);
        s8v bl = *(const s8v*)(g_lo + bbase);
        acc[s] = __builtin_amdgcn_mfma_f32_16x16x32_bf16(ah[kt], bh, acc[s], 0, 0, 0);
        acc[s] = __builtin_amdgcn_mfma_f32_16x16x32_bf16(ah[kt], bl, acc[s], 0, 0, 0);
        acc[s] = __builtin_amdgcn_mfma_f32_16x16x32_bf16(al[kt], bh, acc[s], 0, 0, 0);
      }
    }
    float* sd = sdbuf[pb];
#pragma unroll
    for (int s = 0; s < 4; ++s) {
      int ml = s * 16 + l16;
      float nm = norms[rowb + m0 + ml];
#pragma unroll
      for (int r = 0; r < 4; ++r)
        sd[sdx(wave * 16 + quad * 4 + r, ml)] = nm - 2.f * acc[s][r];
    }
    // prefetch kt=0 B-fragments of the NEXT tile (latency overlaps the scan)
    const int m0n = m0 + 64;
    if (m0n < (part + 1) * PN) {
      const int brgn = (int)((rowb + m0n) >> 4);
#pragma unroll
      for (int s = 0; s < 4; ++s) {
        const size_t bbase = ((size_t)(brgn + s) * KT) * 512 + lane * 8;
        pbh[s] = *(const s8v*)(g_hi + bbase);
        pbl[s] = *(const s8v*)(g_lo + bbase);
      }
    }
    __syncthreads();  // single barrier per tile
    const float T = __uint_as_float(gth);
    const int mbase = m0 + wave * 16;
    const float* srow = sd + lane * 68;
    const int cswz = 4 * ((lane >> 2) & 7);  // read swizzle for row=lane
    unsigned pass = 0;
#pragma unroll
    for (int jj = 0; jj < 16; jj += 4) {
      float4 d4 = *(const float4*)(srow + ((wave * 16 + jj) ^ cswz));
      pass |= (unsigned)(d4.x + qn <= T) << jj;
      pass |= (unsigned)(d4.y + qn <= T) << (jj + 1);
      pass |= (unsigned)(d4.z + qn <= T) << (jj + 2);
      pass |= (unsigned)(d4.w + qn <= T) << (jj + 3);
    }
    if ((unsigned)(selfn - mbase) < 16u) pass &= ~(1u << (selfn - mbase));
    while (pass) {
      int jj = __builtin_ctz(pass);
      pass &= pass - 1;
      int m = mbase + jj;
      float d = fmaxf(srow[(wave * 16 + jj) ^ cswz] + qn, 0.f);
      u64 key = ((u64)__float_as_uint(d) << 32) | (unsigned)m;
      if (key < K[9]) {
        bool prev = true;
#pragma unroll
        for (int s2 = 9; s2 >= 1; --s2) {
          bool sh = key < K[s2 - 1];
          K[s2] = sh ? K[s2 - 1] : (prev ? key : K[s2]);
          prev = sh;
        }
        if (prev) K[0] = key;
      }
    }
    unsigned mine = (unsigned)(K[9] >> 32);
    unsigned old = atomicMin(&g_th[rowb + selfn], mine);
    gth = min(min(gth, old), mine);
  }
  __syncthreads();  // sd dead; reuse sdbuf for merge lists
  u64* mlist = (u64*)sdbuf;
#pragma unroll
  for (int i = 0; i < 10; ++i) mlist[(lane * 4 + wave) * 10 + i] = K[i];
  __syncthreads();
  if (tid < 64) {
    int q = tid;
    int p0 = 0, p1 = 0, p2 = 0, p3 = 0;
    size_t ob = ((rowb + q0 + q) * NPART + part) * 10;
    for (int cnt = 0; cnt < 10; ++cnt) {
      u64 k0 = mlist[(q * 4 + 0) * 10 + p0];
      u64 k1 = mlist[(q * 4 + 1) * 10 + p1];
      u64 k2 = mlist[(q * 4 + 2) * 10 + p2];
      u64 k3 = mlist[(q * 4 + 3) * 10 + p3];
      u64 bk = k0; int bp = 0;
      if (k1 < bk) { bk = k1; bp = 1; }
      if (k2 < bk) { bk = k2; bp = 2; }
      if (k3 < bk) { bk = k3; bp = 3; }
      if (bp == 0) ++p0; else if (bp == 1) ++p1; else if (bp == 2) ++p2; else ++p3;
      g_pk[ob + cnt] = bk;
    }
  }
}

// --- G[chunk][z] = X @ W_half^T via MFMA; A from g_hi/g_lo, B from g_wfh/g_wfl ---
template <int CPAD>
__global__ __launch_bounds__(256) void gmat_mfma(int wbase, int whalf, int BN) {
  constexpr int KT = CPAD >> 5;
  const int tid = threadIdx.x;
  const int wave = tid >> 6, lane = tid & 63;
  const int quad = lane >> 4, l16 = lane & 15;
  const int r0 = blockIdx.x * 64;
  const int chunk = blockIdx.y;
  const int z = blockIdx.z;
  const int wz = wbase + z * whalf;
  const int wrg0 = chunk * 4;
  f32x4 acc[4];
#pragma unroll
  for (int s = 0; s < 4; ++s) acc[s] = (f32x4){0.f, 0.f, 0.f, 0.f};
  const int arg = (r0 >> 4) + wave;
#pragma unroll
  for (int kt = 0; kt < KT; ++kt) {
    const size_t abase = ((size_t)arg * KT + kt) * 512 + lane * 8;
    s8v ah = *(const s8v*)(g_hi + abase);
    s8v al = *(const s8v*)(g_lo + abase);
#pragma unroll
    for (int s = 0; s < 4; ++s) {
      const size_t woff = (size_t)wz + ((size_t)(wrg0 + s) * KT + kt) * 512 + lane * 8;
      s8v bh = *(const s8v*)(g_wfh + woff);
      s8v bl = *(const s8v*)(g_wfl + woff);
      acc[s] = __builtin_amdgcn_mfma_f32_16x16x32_bf16(ah, bh, acc[s], 0, 0, 0);
      acc[s] = __builtin_amdgcn_mfma_f32_16x16x32_bf16(ah, bl, acc[s], 0, 0, 0);
      acc[s] = __builtin_amdgcn_mfma_f32_16x16x32_bf16(al, bh, acc[s], 0, 0, 0);
    }
  }
  float* Gz = g_G + (size_t)(chunk * 2 + z) * BN * 64;
#pragma unroll
  for (int s = 0; s < 4; ++s)
#pragma unroll
    for (int r = 0; r < 4; ++r)
      Gz[(size_t)(r0 + wave * 16 + quad * 4 + r) * 64 + s * 16 + l16] = acc[s][r];
}

// ------- edge-conv epilogue: inline NPART-merge (rank-select) + gather+max
//         + fused splits + norms + g_th re-init. One wave per row.
__global__ void edge_epi64(const void* s, const void* t, int colbase,
                           int knn_csh2, int norms_mode, int BN, int N) {
  __shared__ u64 kbuf[4][40];
  __shared__ int oidx[4][10];
  const int isb = g_flag;
  int tid = threadIdx.x;
  int p = tid >> 6, o = tid & 63;  // p = wave = row-in-block
  int row = blockIdx.x * 4 + p;
  int chunk = blockIdx.y;
  const float* G1 = g_G + (size_t)(chunk * 2 + 0) * BN * 64;
  const float* G2 = g_G + (size_t)(chunk * 2 + 1) * BN * 64;
  int b = row / N;
  if (o < 40) kbuf[p][o] = g_pk[(size_t)row * 40 + o];
  if (o < 40) {
    u64 myk = kbuf[p][o];
    int rank = 0;
#pragma unroll 8
    for (int j = 0; j < 40; ++j) rank += (kbuf[p][j] < myk);
    if (rank < 10) oidx[p][rank] = (int)(myk & 0xFFFFFFFFu);
  }
  float g1n = G1[(size_t)row * 64 + o];
  float base = G2[(size_t)row * 64 + o] - g1n;
  int co = chunk * 64 + o;
  float sv = ldany(s, co, isb), tv = ldany(t, co, isb);
  float mx = -FMAX;
#pragma unroll
  for (int k = 0; k < 10; ++k) {
    int m = oidx[p][k];
    m = (m < 0) ? 0 : ((m >= N) ? N - 1 : m);
    float h = sv * (G1[((size_t)b * N + m) * 64 + o] + base) + tv;
    h = (h >= 0.f) ? h : NEG * h;
    mx = fmaxf(mx, h);
  }
  bf16 h16 = __float2bfloat16(mx);
  float hf = __bfloat162float(h16);
  bf16 l16v = __float2bfloat16(mx - hf);
  unsigned short hu = *(unsigned short*)&h16;
  unsigned short lu = *(unsigned short*)&l16v;
  if (knn_csh2 >= 0) {
    int KTL = 1 << knn_csh2;
    size_t ki = ((size_t)(row >> 4) * KTL + (co >> 5)) * 512 +
                ((size_t)((co >> 3) & 3)) * 128 + (row & 15) * 8 + (co & 7);
    g_hi[ki] = hu; g_lo[ki] = lu;
  }
  {
    int gc = colbase + co;
    size_t wi = ((size_t)(row >> 4) * 16 + (gc >> 5)) * 512 +
                ((size_t)((gc >> 3) & 3)) * 128 + (row & 15) * 8 + (gc & 7);
    g_xhi5[wi] = hu; g_xlo5[wi] = lu;
  }
  if (norms_mode) {
    float ns = mx * mx;
#pragma unroll
    for (int off = 32; off > 0; off >>= 1) ns += __shfl_down(ns, off, 64);
    if (o == 0) {
      if (norms_mode == 1) g_ws_f[OFF_NORMS + row] = ns;
      else atomicAdd(&g_ws_f[OFF_NORMS + row], ns);
      g_th[row] = FMAXB;  // reset bound for next layer's knn
    }
  }
}

// ------- W5 MFMA + max over n; wave tile 64n x 64o (s5>0: affine after max) ----
__global__ __launch_bounds__(256) void w5max_mfma(const void* s5, const void* t5, int N) {
  const int tid = threadIdx.x;
  const int wave = tid >> 6, lane = tid & 63;
  const int quad = lane >> 4, l16 = lane & 15;
  const int b = blockIdx.z;
  const int o0 = blockIdx.y * 64, n0 = blockIdx.x * 256;
  f32x4 acc[4][4];
#pragma unroll
  for (int a = 0; a < 4; ++a)
#pragma unroll
    for (int s = 0; s < 4; ++s) acc[a][s] = (f32x4){0.f, 0.f, 0.f, 0.f};

  const int arg0 = (int)(((size_t)b * N + n0) >> 4) + wave * 4;
  const int wrg0 = o0 >> 4;
  for (int kt = 0; kt < 16; ++kt) {
    s8v ah[4], al[4];
#pragma unroll
    for (int a = 0; a < 4; ++a) {
      const size_t abase = ((size_t)(arg0 + a) * 16 + kt) * 512 + lane * 8;
      ah[a] = *(const s8v*)(g_xhi5 + abase);
      al[a] = *(const s8v*)(g_xlo5 + abase);
    }
#pragma unroll
    for (int s = 0; s < 4; ++s) {
      const size_t bbase = ((size_t)(wrg0 + s) * 16 + kt) * 512 + lane * 8;
      s8v bh = *(const s8v*)(g_whi + bbase);
      s8v bl = *(const s8v*)(g_wlo + bbase);
#pragma unroll
      for (int a = 0; a < 4; ++a) {
        acc[a][s] = __builtin_amdgcn_mfma_f32_16x16x32_bf16(ah[a], bh, acc[a][s], 0, 0, 0);
        acc[a][s] = __builtin_amdgcn_mfma_f32_16x16x32_bf16(ah[a], bl, acc[a][s], 0, 0, 0);
        acc[a][s] = __builtin_amdgcn_mfma_f32_16x16x32_bf16(al[a], bh, acc[a][s], 0, 0, 0);
      }
    }
  }
  __shared__ float red[4][64];
  const int isb = g_flag;
#pragma unroll
  for (int s = 0; s < 4; ++s) {
    float m4 = -FMAX;
#pragma unroll
    for (int a = 0; a < 4; ++a)
#pragma unroll
      for (int r = 0; r < 4; ++r) m4 = fmaxf(m4, acc[a][s][r]);
#pragma unroll
    for (int off = 16; off < 64; off <<= 1) m4 = fmaxf(m4, __shfl_down(m4, off, 64));
    if (quad == 0) red[wave][s * 16 + l16] = m4;
  }
  __syncthreads();
  if (tid < 64) {
    float m = fmaxf(fmaxf(red[0][tid], red[1][tid]), fmaxf(red[2][tid], red[3][tid]));
    int o = o0 + tid;
    float sv = ldany(s5, o, isb), tv = ldany(t5, o, isb);
    float h = sv * m + tv;
    h = (h >= 0.f) ? h : NEG * h;
    g_ws_f[OFF_PART + ((size_t)b * 1024 + o) * 8 + blockIdx.x] = h;
  }
}

__global__ void poolred_kernel() {
  const float* part = g_ws_f + OFF_PART;
  float* pooled = g_ws_f + OFF_POOLED;
  int i = blockIdx.x * blockDim.x + threadIdx.x;
  if (i >= 8 * 1024) return;
  const float* p = part + (size_t)i * 8;
  float m = -FMAX;
#pragma unroll
  for (int j = 0; j < 8; ++j) m = fmaxf(m, p[j]);
  pooled[i] = m;
}

// ---------------- FC: one wave per output ----------------
__global__ void fc_kernel(size_t inoff, const void* W, const void* bias,
                          const void* s, const void* t, size_t outoff, int has_out,
                          void* OUTB, int Bb, int IC, int OC, int act) {
  const int isb = g_flag;
  const float* IN = g_ws_f + inoff;
  int gw = (blockIdx.x * blockDim.x + threadIdx.x) >> 6;
  int lane = threadIdx.x & 63;
  if (gw >= Bb * OC) return;
  int b = gw / OC, o = gw % OC;
  const float* in = IN + (size_t)b * IC;
  float acc = 0.f;
  for (int c = lane; c < IC; c += 64) acc += in[c] * ldany(W, (size_t)o * IC + c, isb);
#pragma unroll
  for (int off = 32; off > 0; off >>= 1) acc += __shfl_down(acc, off, 64);
  if (lane == 0) {
    float h = acc;
    if (bias) h += ldany(bias, o, isb);
    if (s) h = h * ldany(s, o, isb) + ldany(t, o, isb);
    if (act) h = (h >= 0.f) ? h : NEG * h;
    if (has_out) g_ws_f[outoff + (size_t)b * OC + o] = h;
    if (OUTB) {
      if (isb) ((bf16*)OUTB)[(size_t)b * OC + o] = __float2bfloat16(h);
      else ((float*)OUTB)[(size_t)b * OC + o] = h;
    }
  }
}

extern "C" void kernel_launch(void* const* d_in, const int* in_sizes, int n_in,
                              void* d_out, int out_size, void* d_ws, size_t ws_size,
                              hipStream_t stream) {
  const int B = 8, N = 2048, BN = B * N;
  const void* points = d_in[0];
  const void *W1 = d_in[1], *s1 = d_in[2], *t1 = d_in[3];
  const void *W2 = d_in[4], *s2 = d_in[5], *t2 = d_in[6];
  const void *W3 = d_in[7], *s3 = d_in[8], *t3 = d_in[9];
  const void *W4 = d_in[10], *s4 = d_in[11], *t4 = d_in[12];
  const void *W5 = d_in[13], *s5 = d_in[14], *t5 = d_in[15];
  const void *Wf1 = d_in[16], *sf1 = d_in[17], *tf1 = d_in[18];
  const void *Wf2 = d_in[19], *bf2 = d_in[20], *sf2 = d_in[21], *tf2 = d_in[22];
  const void *Wf3 = d_in[23], *bf3 = d_in[24];

  probe_kernel<<<1, 1, 0, stream>>>(points);
  split_kernel<<<(1024 * 512) / 256, 256, 0, stream>>>(W5, 512, 512, 4, 1, 1024 * 512);
  split_w<<<dim3(2048 / 256, 2), 256, 0, stream>>>(W1, 3, 0, WB1, 2048, 2048);
  split_w<<<dim3(4096 / 256, 2), 256, 0, stream>>>(W2, 64, 1, WB2, 4096, 4096);
  split_w<<<dim3(8192 / 256, 2), 256, 0, stream>>>(W3, 64, 1, WB3, 8192, 8192);
  split_w<<<dim3(32768 / 256, 2), 256, 0, stream>>>(W4, 128, 2, WB4, 32768, 32768);

  // ---- layer 1: points (C=3, CPAD=32) -> cols 0:64
  norms_kernel<<<BN / 4, 256, 0, stream>>>(points, 3, 3, BN);
  split_kernel<<<(BN * 32) / 256, 256, 0, stream>>>(points, 3, 3, 0, 0, BN * 32);
  knn_fused<32><<<dim3(N / 64, B, NPART), 256, 0, stream>>>(N);
  gmat_mfma<32><<<dim3(BN / 64, 1, 2), 256, 0, stream>>>(WB1, 2048, BN);
  edge_epi64<<<dim3(BN / 4, 1), 256, 0, stream>>>(s1, t1, 0, 1, 1, BN, N);
  // ---- layer 2: (C=64, CPAD=64) -> cols 64:128
  knn_fused<64><<<dim3(N / 64, B, NPART), 256, 0, stream>>>(N);
  gmat_mfma<64><<<dim3(BN / 64, 1, 2), 256, 0, stream>>>(WB2, 4096, BN);
  edge_epi64<<<dim3(BN / 4, 1), 256, 0, stream>>>(s2, t2, 64, 1, 1, BN, N);
  // ---- layer 3: (C=64) -> cols 128:256, 2 chunks; next layer CPAD=128
  knn_fused<64><<<dim3(N / 64, B, NPART), 256, 0, stream>>>(N);
  gmat_mfma<64><<<dim3(BN / 64, 2, 2), 256, 0, stream>>>(WB3, 8192, BN);
  zero_norms<<<BN / 256, 256, 0, stream>>>();
  edge_epi64<<<dim3(BN / 4, 2), 256, 0, stream>>>(s3, t3, 128, 2, 2, BN, N);
  // ---- layer 4: (C=128) -> cols 256:512, 4 chunks; no next knn
  knn_fused<128><<<dim3(N / 64, B, NPART), 256, 0, stream>>>(N);
  gmat_mfma<128><<<dim3(BN / 64, 4, 2), 256, 0, stream>>>(WB4, 32768, BN);
  edge_epi64<<<dim3(BN / 4, 4), 256, 0, stream>>>(s4, t4, 256, -1, 0, BN, N);
  // ---- W5 + global max pool
  w5max_mfma<<<dim3(8, 16, 8), 256, 0, stream>>>(s5, t5, N);
  poolred_kernel<<<32, 256, 0, stream>>>();
  // ---- FC head
  fc_kernel<<<(8 * 512 * 64) / 256, 256, 0, stream>>>(OFF_POOLED, Wf1, nullptr, sf1, tf1, OFF_H1, 1, nullptr, 8, 1024, 512, 1);
  fc_kernel<<<(8 * 256 * 64) / 256, 256, 0, stream>>>(OFF_H1, Wf2, bf2, sf2, tf2, OFF_H2, 1, nullptr, 8, 512, 256, 1);
  fc_kernel<<<6, 256, 0, stream>>>(OFF_H2, Wf3, bf3, nullptr, nullptr, 0, 0, d_out, 8, 256, 3, 0);
}